// Round 5
// baseline (32.022 us; speedup 1.0000x reference)
//
#include <hip/hip_runtime.h>

// Problem constants (fixed by reference setup_inputs): D=32 detectors,
// in_s = out_s = 64, row stride 2048 floats, B = 8192.
#define NDET    32
#define SEG     64
#define ROWLEN  2048
#define TILE_B  128
#define THREADS 256
#define LSTRIDE 72   // LDS row stride in bf16 (144 B, 16B-aligned, padded)

typedef __bf16 bf16x8 __attribute__((ext_vector_type(8)));
typedef __bf16 bf16x4 __attribute__((ext_vector_type(4)));
typedef float  f32x4  __attribute__((ext_vector_type(4)));

__device__ __forceinline__ bf16x4 cvt4(f32x4 a) {
  bf16x4 r;
  r[0] = (__bf16)a[0]; r[1] = (__bf16)a[1]; r[2] = (__bf16)a[2]; r[3] = (__bf16)a[3];
  return r;
}

__device__ __forceinline__ bf16x8 cvt8(f32x4 a, f32x4 b) {
  bf16x8 r;
  r[0] = (__bf16)a[0]; r[1] = (__bf16)a[1]; r[2] = (__bf16)a[2]; r[3] = (__bf16)a[3];
  r[4] = (__bf16)b[0]; r[5] = (__bf16)b[1]; r[6] = (__bf16)b[2]; r[7] = (__bf16)b[3];
  return r;
}

// y[b, d*64+o] = sum_i x[b, d*64+i] * W[d*64+o, d*64+i]
//
// v5: x staged via LDS with the coalesced-optimum mapping (per instruction,
// each 16-lane group reads one COMPLETE 256B row window); W fragments load
// straight to registers (scattered 16B but L2-hot, once per block); y stored
// nontemporal so the 64MB/run write stream doesn't evict x from L3.
__global__ __launch_bounds__(THREADS, 6) void ensemble_linear_v5(
    const float* __restrict__ x, const float* __restrict__ W,
    float* __restrict__ y) {
  const int d     = blockIdx.y;
  const int b0    = blockIdx.x * TILE_B;
  const int t     = threadIdx.x;
  const int lane  = t & 63;
  const int wid   = t >> 6;        // 0..3
  const int dbase = d * SEG;

  const int rq  = lane >> 4;       // staging: row within 4-row quad
  const int c4  = lane & 15;       // staging: 16B chunk within 256B row
  const int m16 = lane & 15;       // fragment M/N index
  const int kg  = lane >> 4;       // fragment k-group

  __shared__ __bf16 xls[TILE_B * LSTRIDE];   // 18432 B (x only)

  // ---- issue all 8 x loads up front (coalesced: 4 complete rows/instr) ----
  f32x4 xv[8];
#pragma unroll
  for (int p = 0; p < 8; ++p) {
    const int row = wid * 32 + p * 4 + rq;
    xv[p] = *(const f32x4*)(x + (size_t)(b0 + row) * ROWLEN + dbase + c4 * 4);
  }

  // ---- W fragments direct to registers (L2-hot; convert per-g) ----
  // lane holds W[dbase + g*16 + m16][dbase + kh*32 + kg*8 + j], j=0..7
  bf16x8 wfrag[4][2];
#pragma unroll
  for (int g = 0; g < 4; ++g) {
    const float* wp = W + (size_t)(dbase + g * 16 + m16) * ROWLEN + dbase + kg * 8;
    f32x4 wa0 = *(const f32x4*)(wp);
    f32x4 wa1 = *(const f32x4*)(wp + 4);
    f32x4 wb0 = *(const f32x4*)(wp + 32);
    f32x4 wb1 = *(const f32x4*)(wp + 36);
    wfrag[g][0] = cvt8(wa0, wa1);
    wfrag[g][1] = cvt8(wb0, wb1);
  }

  // ---- convert + stage x to LDS ----
#pragma unroll
  for (int p = 0; p < 8; ++p) {
    const int row = wid * 32 + p * 4 + rq;
    *(bf16x4*)(&xls[row * LSTRIDE + c4 * 4]) = cvt4(xv[p]);
  }

  __syncthreads();   // the only barrier

  // ---- compute: wave owns rows [wid*32, wid*32+32), 2 sub-tiles of 16 ----
  // Swapped-operand MFMA (r3-verified): D = W_tile . x_tile^T.
#pragma unroll
  for (int s = 0; s < 2; ++s) {
    const int rbase = wid * 32 + s * 16;
    bf16x8 a0 = *(const bf16x8*)(&xls[(rbase + m16) * LSTRIDE + kg * 8]);        // k 0..31
    bf16x8 a1 = *(const bf16x8*)(&xls[(rbase + m16) * LSTRIDE + 32 + kg * 8]);   // k 32..63

    float* yp = y + (size_t)(b0 + rbase + m16) * ROWLEN + dbase + kg * 4;
#pragma unroll
    for (int g = 0; g < 4; ++g) {
      f32x4 acc = (f32x4){0.f, 0.f, 0.f, 0.f};
      acc = __builtin_amdgcn_mfma_f32_16x16x32_bf16(wfrag[g][0], a0, acc, 0, 0, 0);
      acc = __builtin_amdgcn_mfma_f32_16x16x32_bf16(wfrag[g][1], a1, acc, 0, 0, 0);
      __builtin_nontemporal_store(acc, (f32x4*)(yp + g * 16));
    }
  }
}

extern "C" void kernel_launch(void* const* d_in, const int* in_sizes, int n_in,
                              void* d_out, int out_size, void* d_ws, size_t ws_size,
                              hipStream_t stream) {
  const float* x = (const float*)d_in[0];
  const float* W = (const float*)d_in[1];
  float* y = (float*)d_out;
  const int B = in_sizes[0] / ROWLEN;   // 8192
  dim3 grid(B / TILE_B, NDET);
  ensemble_linear_v5<<<grid, dim3(THREADS), 0, stream>>>(x, W, y);
}